// Round 2
// baseline (772.570 us; speedup 1.0000x reference)
//
#include <hip/hip_runtime.h>
#include <hip/hip_bf16.h>
#include <cstdint>

#define NN 20000
#define NE 200000
#define NG 128
#define HID 512
#define XLR_W 1024

typedef __attribute__((ext_vector_type(4))) float f32x4;
typedef __attribute__((ext_vector_type(8))) short s16x8;

__device__ __forceinline__ float bf2f(unsigned short u) {
  union { unsigned int i; float f; } v; v.i = ((unsigned int)u) << 16; return v.f;
}
__device__ __forceinline__ unsigned short f2bf(float f) {
  union { float f; unsigned int i; } v; v.f = f;
  unsigned int i = v.i + 0x7FFFu + ((v.i >> 16) & 1u);
  return (unsigned short)(i >> 16);
}

// ---------------- fp32 -> bf16 cast (x is already bf16-rounded, so exact) ----------------
__global__ void k_cast(const float* __restrict__ in, unsigned short* __restrict__ out, int n4) {
  int i = blockIdx.x * blockDim.x + threadIdx.x;
  if (i < n4) {
    float4 v = ((const float4*)in)[i];
    ushort4 o;
    o.x = f2bf(v.x); o.y = f2bf(v.y); o.z = f2bf(v.z); o.w = f2bf(v.w);
    ((ushort4*)out)[i] = o;
  }
}

// ---------------- CSR build ----------------
__global__ void k_hist(const int* __restrict__ dst, int* __restrict__ deg, int E) {
  int i = blockIdx.x * blockDim.x + threadIdx.x;
  if (i < E) atomicAdd(&deg[dst[i]], 1);
}

__global__ void k_scan(const int* __restrict__ deg, int* __restrict__ offs,
                       int* __restrict__ woff, int n) {
  __shared__ int buf[1024];
  __shared__ int carry;
  int t = threadIdx.x;
  if (t == 0) carry = 0;
  __syncthreads();
  for (int base = 0; base < n; base += 1024) {
    int i = base + t;
    int v = (i < n) ? deg[i] : 0;
    buf[t] = v;
    __syncthreads();
    for (int off = 1; off < 1024; off <<= 1) {
      int x = (t >= off) ? buf[t - off] : 0;
      __syncthreads();
      buf[t] += x;
      __syncthreads();
    }
    int ex = buf[t] - v + carry;
    if (i < n) { offs[i] = ex; woff[i] = ex; }
    __syncthreads();
    if (t == 1023) carry += buf[1023];
    __syncthreads();
  }
  if (t == 0) offs[n] = carry;
}

__global__ void k_scatter(const int* __restrict__ src, const int* __restrict__ dst,
                          int* __restrict__ woff, int* __restrict__ src_s,
                          int* __restrict__ dst_s, int E) {
  int i = blockIdx.x * blockDim.x + threadIdx.x;
  if (i < E) {
    int d = dst[i];
    int pos = atomicAdd(&woff[d], 1);
    src_s[pos] = src[i];
    dst_s[pos] = d;
  }
}

// ---------------- weight pack: wt[n][k] = W[k][n] (bf16), n in [0,1024) = Wl||Wr ----------------
__global__ void k_pack(const float* __restrict__ Wl, const float* __restrict__ bl,
                       const float* __restrict__ Wr, const float* __restrict__ br,
                       unsigned short* __restrict__ wt, float* __restrict__ bcat, int K) {
  int id = blockIdx.x * blockDim.x + threadIdx.x;
  int total = XLR_W * K;
  if (id < total) {
    int nrow = id / K, k = id - nrow * K;
    float v = (nrow < HID) ? Wl[k * HID + nrow] : Wr[k * HID + (nrow - HID)];
    wt[id] = f2bf(v);
  }
  if (id < XLR_W) bcat[id] = (id < HID) ? bl[id] : br[id - HID];
}

// ---------------- GEMM: C[M,N] = A[M,K] @ Bt[N,K]^T + bias, bf16 in/out, f32 acc ----------------
#define BM 128
#define BN 128
#define BK 32
#define LSTR 40

__global__ __launch_bounds__(256, 2) void k_gemm(const unsigned short* __restrict__ A,
                                                 const unsigned short* __restrict__ Bt,
                                                 const float* __restrict__ bias,
                                                 unsigned short* __restrict__ C,
                                                 int M, int N, int K) {
  __shared__ __align__(16) unsigned short As[BM * LSTR];
  __shared__ __align__(16) unsigned short Bs[BN * LSTR];
  int m0 = blockIdx.y * BM, n0 = blockIdx.x * BN;
  int t = threadIdx.x;
  int wave = t >> 6, lane = t & 63;
  int wm = (wave >> 1) * 64, wn = (wave & 1) * 64;
  int ml = lane & 15, mq = lane >> 4;
  int srow = t >> 2;
  int scol = (t & 3) * 8;

  f32x4 acc[4][4];
#pragma unroll
  for (int i = 0; i < 4; i++)
#pragma unroll
    for (int j = 0; j < 4; j++) acc[i][j] = (f32x4)0.0f;

  int ar0 = m0 + srow; if (ar0 > M - 1) ar0 = M - 1;
  int ar1 = m0 + srow + 64; if (ar1 > M - 1) ar1 = M - 1;
  const int4* a0p = (const int4*)(A + (size_t)ar0 * K + scol);
  const int4* a1p = (const int4*)(A + (size_t)ar1 * K + scol);
  const int4* b0p = (const int4*)(Bt + (size_t)(n0 + srow) * K + scol);
  const int4* b1p = (const int4*)(Bt + (size_t)(n0 + srow + 64) * K + scol);

  for (int k0 = 0; k0 < K; k0 += BK) {
    int4 av0 = *a0p; int4 av1 = *a1p; int4 bv0 = *b0p; int4 bv1 = *b1p;
    a0p += BK / 8; a1p += BK / 8; b0p += BK / 8; b1p += BK / 8;
    *(int4*)(&As[srow * LSTR + scol]) = av0;
    *(int4*)(&As[(srow + 64) * LSTR + scol]) = av1;
    *(int4*)(&Bs[srow * LSTR + scol]) = bv0;
    *(int4*)(&Bs[(srow + 64) * LSTR + scol]) = bv1;
    __syncthreads();
    s16x8 af[4], bfr[4];
#pragma unroll
    for (int i = 0; i < 4; i++)
      af[i] = *(const s16x8*)(&As[(wm + i * 16 + ml) * LSTR + mq * 8]);
#pragma unroll
    for (int j = 0; j < 4; j++)
      bfr[j] = *(const s16x8*)(&Bs[(wn + j * 16 + ml) * LSTR + mq * 8]);
#pragma unroll
    for (int i = 0; i < 4; i++)
#pragma unroll
      for (int j = 0; j < 4; j++)
        acc[i][j] = __builtin_amdgcn_mfma_f32_16x16x32_bf16(af[i], bfr[j], acc[i][j], 0, 0, 0);
    __syncthreads();
  }

#pragma unroll
  for (int i = 0; i < 4; i++) {
#pragma unroll
    for (int j = 0; j < 4; j++) {
      int col = n0 + wn + j * 16 + ml;
      float bcol = bias[col];
#pragma unroll
      for (int r = 0; r < 4; r++) {
        int row = m0 + wm + i * 16 + mq * 4 + r;
        if (row < M) C[(size_t)row * N + col] = f2bf(acc[i][j][r] + bcol);
      }
    }
  }
}

// ---------------- pass A: per-edge logits (wave per edge) ----------------
__global__ __launch_bounds__(256) void k_logits(const unsigned short* __restrict__ xlr,
                                                const float* __restrict__ att,
                                                const int* __restrict__ src_s,
                                                const int* __restrict__ dst_s,
                                                float* __restrict__ logits, int E) {
  int wid = blockIdx.x * 4 + (threadIdx.x >> 6);
  int lane = threadIdx.x & 63;
  if (wid >= E) return;
  int s = src_s[wid], d = dst_s[wid];
  const unsigned short* ps = xlr + (size_t)s * XLR_W;
  const unsigned short* pd = xlr + (size_t)d * XLR_W + HID;
#pragma unroll
  for (int h = 0; h < 8; h++) {
    float v = bf2f(ps[h * 64 + lane]) + bf2f(pd[h * 64 + lane]);
    v = v > 0.0f ? v : 0.2f * v;
    float p = v * att[h * 64 + lane];
#pragma unroll
    for (int off = 32; off > 0; off >>= 1) p += __shfl_xor(p, off, 64);
    if (lane == 0) logits[(size_t)wid * 8 + h] = p;
  }
}

// ---------------- pass B: segment softmax per (node, head) ----------------
__global__ __launch_bounds__(256) void k_softmax(float* __restrict__ logits,
                                                 float* __restrict__ dinv,
                                                 const int* __restrict__ offs) {
  int id = blockIdx.x * blockDim.x + threadIdx.x;
  if (id >= NN * 8) return;
  int n = id >> 3, h = id & 7;
  int s = offs[n], e = offs[n + 1];
  float m = -3.0e38f;
  for (int i = s; i < e; i++) m = fmaxf(m, logits[i * 8 + h]);
  float sum = 0.0f;
  for (int i = s; i < e; i++) {
    float p = __expf(logits[i * 8 + h] - m);
    logits[i * 8 + h] = p;
    sum += p;
  }
  dinv[id] = 1.0f / (sum + 1e-16f);
}

// ---------------- pass C: aggregate + bias + ELU (block per node) ----------------
__global__ __launch_bounds__(256) void k_aggregate(const unsigned short* __restrict__ xlr,
                                                   const float* __restrict__ alpha,
                                                   const float* __restrict__ dinv,
                                                   const int* __restrict__ offs,
                                                   const int* __restrict__ src_s,
                                                   const float* __restrict__ bias,
                                                   unsigned short* __restrict__ hout) {
  int n = blockIdx.x;
  int wave = threadIdx.x >> 6, lane = threadIdx.x & 63;
  int s0 = offs[n], s1 = offs[n + 1];
#pragma unroll
  for (int hh = 0; hh < 2; hh++) {
    int h = wave + hh * 4;
    float di = dinv[n * 8 + h];
    float acc = 0.0f;
    for (int i = s0; i < s1; i++) {
      float a = alpha[i * 8 + h];
      int s = src_s[i];
      acc += a * bf2f(xlr[(size_t)s * XLR_W + h * 64 + lane]);
    }
    acc *= di;
    float v = acc + bias[h * 64 + lane];
    v = v > 0.0f ? v : (expf(v) - 1.0f);
    hout[(size_t)n * HID + h * 64 + lane] = f2bf(v);
  }
}

// ---------------- pool (+BN) and FC ----------------
__device__ __forceinline__ int lower_bound(const int* __restrict__ a, int n, int key) {
  int lo = 0, hi = n;
  while (lo < hi) { int mid = (lo + hi) >> 1; if (a[mid] < key) lo = mid + 1; else hi = mid; }
  return lo;
}

__global__ __launch_bounds__(256) void k_pool_bn(const unsigned short* __restrict__ h,
                                                 const int* __restrict__ batch,
                                                 const float* __restrict__ gamma,
                                                 const float* __restrict__ beta,
                                                 const float* __restrict__ mean,
                                                 const float* __restrict__ var,
                                                 float* __restrict__ gbn) {
  int g = blockIdx.x, t = threadIdx.x;
  int start = lower_bound(batch, NN, g);
  int end = lower_bound(batch, NN, g + 1);
  float a0 = 0.0f, a1 = 0.0f;
  for (int n = start; n < end; n++) {
    a0 += bf2f(h[(size_t)n * HID + t]);
    a1 += bf2f(h[(size_t)n * HID + t + 256]);
  }
  int c0 = t, c1 = t + 256;
  float v0 = (a0 - mean[c0]) * rsqrtf(var[c0] + 1e-5f) * gamma[c0] + beta[c0];
  float v1 = (a1 - mean[c1]) * rsqrtf(var[c1] + 1e-5f) * gamma[c1] + beta[c1];
  gbn[(size_t)g * HID + c0] = v0;
  gbn[(size_t)g * HID + c1] = v1;
}

__global__ __launch_bounds__(256) void k_fc(const float* __restrict__ gbn,
                                            const float* __restrict__ Wfc,
                                            const float* __restrict__ bfc,
                                            float* __restrict__ out) {
  __shared__ float xs[512];
  int g = blockIdx.x, t = threadIdx.x;
  xs[t] = gbn[g * 512 + t];
  xs[t + 256] = gbn[g * 512 + t + 256];
  __syncthreads();
  float acc = bfc[t];
#pragma unroll 8
  for (int k = 0; k < 512; k++) acc += xs[k] * Wfc[k * 256 + t];
  out[g * 256 + t] = acc;
}

extern "C" void kernel_launch(void* const* d_in, const int* in_sizes, int n_in,
                              void* d_out, int out_size, void* d_ws, size_t ws_size,
                              hipStream_t stream) {
  const float* x     = (const float*)d_in[0];
  const int* ei      = (const int*)d_in[1];
  const int* batch   = (const int*)d_in[2];
  const float* Wl0   = (const float*)d_in[3];
  const float* bl0   = (const float*)d_in[4];
  const float* Wr0   = (const float*)d_in[5];
  const float* br0   = (const float*)d_in[6];
  const float* att0  = (const float*)d_in[7];
  const float* bias0 = (const float*)d_in[8];
  const float* Wl1   = (const float*)d_in[9];
  const float* bl1   = (const float*)d_in[10];
  const float* Wr1   = (const float*)d_in[11];
  const float* br1   = (const float*)d_in[12];
  const float* att1  = (const float*)d_in[13];
  const float* bias1 = (const float*)d_in[14];
  const float* gamma = (const float*)d_in[15];
  const float* beta  = (const float*)d_in[16];
  const float* mean  = (const float*)d_in[17];
  const float* var   = (const float*)d_in[18];
  const float* Wfc   = (const float*)d_in[19];
  const float* bfc   = (const float*)d_in[20];

  const int* src = ei;
  const int* dst = ei + NE;

  char* w = (char*)d_ws;
  size_t off = 0;
  auto alloc = [&](size_t bytes) -> void* {
    void* p = w + off;
    off += (bytes + 255) & ~(size_t)255;
    return p;
  };
  int* deg            = (int*)alloc((size_t)NN * 4);
  int* offs           = (int*)alloc((size_t)(NN + 1) * 4);
  int* woff           = (int*)alloc((size_t)NN * 4);
  int* src_s          = (int*)alloc((size_t)NE * 4);
  int* dst_s          = (int*)alloc((size_t)NE * 4);
  float* logit        = (float*)alloc((size_t)NE * 8 * 4);
  float* dinv         = (float*)alloc((size_t)NN * 8 * 4);
  unsigned short* xb  = (unsigned short*)alloc((size_t)NN * 256 * 2);
  unsigned short* xlr = (unsigned short*)alloc((size_t)NN * XLR_W * 2);
  unsigned short* hb  = (unsigned short*)alloc((size_t)NN * HID * 2);
  unsigned short* wt  = (unsigned short*)alloc((size_t)XLR_W * HID * 2);
  float* bcat         = (float*)alloc((size_t)XLR_W * 4);
  float* gbn          = (float*)alloc((size_t)NG * HID * 4);

  hipMemsetAsync(deg, 0, (size_t)NN * 4, stream);
  k_hist<<<(NE + 255) / 256, 256, 0, stream>>>(dst, deg, NE);
  k_scan<<<1, 1024, 0, stream>>>(deg, offs, woff, NN);
  k_scatter<<<(NE + 255) / 256, 256, 0, stream>>>(src, dst, woff, src_s, dst_s, NE);

  k_cast<<<(NN * 256 / 4 + 255) / 256, 256, 0, stream>>>(x, xb, NN * 256 / 4);

  // layer 0
  k_pack<<<(XLR_W * 256 + 255) / 256, 256, 0, stream>>>(Wl0, bl0, Wr0, br0, wt, bcat, 256);
  k_gemm<<<dim3(XLR_W / BN, (NN + BM - 1) / BM), 256, 0, stream>>>(xb, wt, bcat, xlr, NN, XLR_W, 256);
  k_logits<<<NE / 4, 256, 0, stream>>>(xlr, att0, src_s, dst_s, logit, NE);
  k_softmax<<<(NN * 8 + 255) / 256, 256, 0, stream>>>(logit, dinv, offs);
  k_aggregate<<<NN, 256, 0, stream>>>(xlr, logit, dinv, offs, src_s, bias0, hb);

  // layer 1
  k_pack<<<(XLR_W * 512 + 255) / 256, 256, 0, stream>>>(Wl1, bl1, Wr1, br1, wt, bcat, 512);
  k_gemm<<<dim3(XLR_W / BN, (NN + BM - 1) / BM), 256, 0, stream>>>(hb, wt, bcat, xlr, NN, XLR_W, 512);
  k_logits<<<NE / 4, 256, 0, stream>>>(xlr, att1, src_s, dst_s, logit, NE);
  k_softmax<<<(NN * 8 + 255) / 256, 256, 0, stream>>>(logit, dinv, offs);
  k_aggregate<<<NN, 256, 0, stream>>>(xlr, logit, dinv, offs, src_s, bias1, hb);

  k_pool_bn<<<NG, 256, 0, stream>>>(hb, batch, gamma, beta, mean, var, gbn);
  k_fc<<<NG, 256, 0, stream>>>(gbn, Wfc, bfc, (float*)d_out);
}

// Round 3
// 543.669 us; speedup vs baseline: 1.4210x; 1.4210x over previous
//
#include <hip/hip_runtime.h>
#include <hip/hip_bf16.h>
#include <cstdint>

#define NN 20000
#define NE 200000
#define NG 128
#define HID 512
#define XLR_W 1024

typedef __attribute__((ext_vector_type(4))) float f32x4;
typedef __attribute__((ext_vector_type(8))) short s16x8;

__device__ __forceinline__ float bf2f(unsigned short u) {
  union { unsigned int i; float f; } v; v.i = ((unsigned int)u) << 16; return v.f;
}
__device__ __forceinline__ unsigned short f2bf(float f) {
  union { float f; unsigned int i; } v; v.f = f;
  unsigned int i = v.i + 0x7FFFu + ((v.i >> 16) & 1u);
  return (unsigned short)(i >> 16);
}

// ---------------- fp32 -> bf16 cast (values already bf16-rounded, so exact) ----------------
__global__ void k_cast(const float* __restrict__ in, unsigned short* __restrict__ out, int n4) {
  int i = blockIdx.x * blockDim.x + threadIdx.x;
  if (i < n4) {
    float4 v = ((const float4*)in)[i];
    ushort4 o;
    o.x = f2bf(v.x); o.y = f2bf(v.y); o.z = f2bf(v.z); o.w = f2bf(v.w);
    ((ushort4*)out)[i] = o;
  }
}

// ---------------- CSR build ----------------
__global__ void k_hist(const int* __restrict__ dst, int* __restrict__ deg, int E) {
  int i = blockIdx.x * blockDim.x + threadIdx.x;
  if (i < E) atomicAdd(&deg[dst[i]], 1);
}

__global__ void k_scan(const int* __restrict__ deg, int* __restrict__ offs,
                       int* __restrict__ woff, int n) {
  __shared__ int buf[1024];
  __shared__ int carry;
  int t = threadIdx.x;
  if (t == 0) carry = 0;
  __syncthreads();
  for (int base = 0; base < n; base += 1024) {
    int i = base + t;
    int v = (i < n) ? deg[i] : 0;
    buf[t] = v;
    __syncthreads();
    for (int off = 1; off < 1024; off <<= 1) {
      int x = (t >= off) ? buf[t - off] : 0;
      __syncthreads();
      buf[t] += x;
      __syncthreads();
    }
    int ex = buf[t] - v + carry;
    if (i < n) { offs[i] = ex; woff[i] = ex; }
    __syncthreads();
    if (t == 1023) carry += buf[1023];
    __syncthreads();
  }
  if (t == 0) offs[n] = carry;
}

__global__ void k_scatter(const int* __restrict__ src, const int* __restrict__ dst,
                          int* __restrict__ woff, int* __restrict__ src_s, int E) {
  int i = blockIdx.x * blockDim.x + threadIdx.x;
  if (i < E) {
    int d = dst[i];
    int pos = atomicAdd(&woff[d], 1);
    src_s[pos] = src[i];
  }
}

// ---------------- weight pack: wt[n][k] = W[k][n] (bf16), n in [0,1024) = Wl||Wr ----------------
__global__ void k_pack(const float* __restrict__ Wl, const float* __restrict__ bl,
                       const float* __restrict__ Wr, const float* __restrict__ br,
                       unsigned short* __restrict__ wt, float* __restrict__ bcat, int K) {
  int id = blockIdx.x * blockDim.x + threadIdx.x;
  int total = XLR_W * K;
  if (id < total) {
    int nrow = id / K, k = id - nrow * K;
    float v = (nrow < HID) ? Wl[k * HID + nrow] : Wr[k * HID + (nrow - HID)];
    wt[id] = f2bf(v);
  }
  if (id < XLR_W) bcat[id] = (id < HID) ? bl[id] : br[id - HID];
}

// ---------------- GEMM: C[M,N] = A[M,K] @ Bt[N,K]^T + bias, bf16 in/out, f32 acc ----------------
#define BM 128
#define BN 128
#define BK 32
#define LSTR 40

__global__ __launch_bounds__(256, 2) void k_gemm(const unsigned short* __restrict__ A,
                                                 const unsigned short* __restrict__ Bt,
                                                 const float* __restrict__ bias,
                                                 unsigned short* __restrict__ C,
                                                 int M, int N, int K) {
  __shared__ __align__(16) unsigned short As[BM * LSTR];
  __shared__ __align__(16) unsigned short Bs[BN * LSTR];
  int m0 = blockIdx.y * BM, n0 = blockIdx.x * BN;
  int t = threadIdx.x;
  int wave = t >> 6, lane = t & 63;
  int wm = (wave >> 1) * 64, wn = (wave & 1) * 64;
  int ml = lane & 15, mq = lane >> 4;
  int srow = t >> 2;
  int scol = (t & 3) * 8;

  f32x4 acc[4][4];
#pragma unroll
  for (int i = 0; i < 4; i++)
#pragma unroll
    for (int j = 0; j < 4; j++) acc[i][j] = (f32x4)0.0f;

  int ar0 = m0 + srow; if (ar0 > M - 1) ar0 = M - 1;
  int ar1 = m0 + srow + 64; if (ar1 > M - 1) ar1 = M - 1;
  const int4* a0p = (const int4*)(A + (size_t)ar0 * K + scol);
  const int4* a1p = (const int4*)(A + (size_t)ar1 * K + scol);
  const int4* b0p = (const int4*)(Bt + (size_t)(n0 + srow) * K + scol);
  const int4* b1p = (const int4*)(Bt + (size_t)(n0 + srow + 64) * K + scol);

  for (int k0 = 0; k0 < K; k0 += BK) {
    int4 av0 = *a0p; int4 av1 = *a1p; int4 bv0 = *b0p; int4 bv1 = *b1p;
    a0p += BK / 8; a1p += BK / 8; b0p += BK / 8; b1p += BK / 8;
    *(int4*)(&As[srow * LSTR + scol]) = av0;
    *(int4*)(&As[(srow + 64) * LSTR + scol]) = av1;
    *(int4*)(&Bs[srow * LSTR + scol]) = bv0;
    *(int4*)(&Bs[(srow + 64) * LSTR + scol]) = bv1;
    __syncthreads();
    s16x8 af[4], bfr[4];
#pragma unroll
    for (int i = 0; i < 4; i++)
      af[i] = *(const s16x8*)(&As[(wm + i * 16 + ml) * LSTR + mq * 8]);
#pragma unroll
    for (int j = 0; j < 4; j++)
      bfr[j] = *(const s16x8*)(&Bs[(wn + j * 16 + ml) * LSTR + mq * 8]);
#pragma unroll
    for (int i = 0; i < 4; i++)
#pragma unroll
      for (int j = 0; j < 4; j++)
        acc[i][j] = __builtin_amdgcn_mfma_f32_16x16x32_bf16(af[i], bfr[j], acc[i][j], 0, 0, 0);
    __syncthreads();
  }

#pragma unroll
  for (int i = 0; i < 4; i++) {
#pragma unroll
    for (int j = 0; j < 4; j++) {
      int col = n0 + wn + j * 16 + ml;
      float bcol = bias[col];
#pragma unroll
      for (int r = 0; r < 4; r++) {
        int row = m0 + wm + i * 16 + mq * 4 + r;
        if (row < M) C[(size_t)row * N + col] = f2bf(acc[i][j][r] + bcol);
      }
    }
  }
}

// ---------------- fused attention: logits + online softmax + aggregate + bias + ELU ----------------
// block per dst node; 4 waves x 2 heads each; xr[dst], att register-resident.
__global__ __launch_bounds__(256) void k_attn(const unsigned short* __restrict__ xlr,
                                              const float* __restrict__ att,
                                              const int* __restrict__ offs,
                                              const int* __restrict__ src_s,
                                              const float* __restrict__ bias,
                                              unsigned short* __restrict__ hout) {
  int n = blockIdx.x;
  int wave = threadIdx.x >> 6, lane = threadIdx.x & 63;
  int c0 = wave * 64 + lane;        // head h0 = wave
  int c1 = (wave + 4) * 64 + lane;  // head h1 = wave + 4
  int s0 = offs[n], s1 = offs[n + 1];

  const unsigned short* xrow = xlr + (size_t)n * XLR_W + HID;
  float xr0 = bf2f(xrow[c0]);
  float xr1 = bf2f(xrow[c1]);
  float a0 = att[c0], a1 = att[c1];

  float m0 = -3.0e38f, m1 = -3.0e38f;
  float sum0 = 0.0f, sum1 = 0.0f, acc0 = 0.0f, acc1 = 0.0f;

  // 2-deep pipeline: index i+1 prefetched, xl of i prefetched
  int sA = (s0 < s1) ? src_s[s0] : 0;
  float xl0 = 0.0f, xl1 = 0.0f;
  if (s0 < s1) {
    const unsigned short* p = xlr + (size_t)sA * XLR_W;
    xl0 = bf2f(p[c0]);
    xl1 = bf2f(p[c1]);
  }
  int sB = (s0 + 1 < s1) ? src_s[s0 + 1] : 0;

  for (int i = s0; i < s1; i++) {
    float cx0 = xl0, cx1 = xl1;
    // prefetch next edge's features and the index after that
    if (i + 1 < s1) {
      const unsigned short* p = xlr + (size_t)sB * XLR_W;
      xl0 = bf2f(p[c0]);
      xl1 = bf2f(p[c1]);
    }
    if (i + 2 < s1) sB = src_s[i + 2];

    float v0 = cx0 + xr0; v0 = v0 > 0.0f ? v0 : 0.2f * v0;
    float v1 = cx1 + xr1; v1 = v1 > 0.0f ? v1 : 0.2f * v1;
    float l0 = v0 * a0, l1 = v1 * a1;
#pragma unroll
    for (int off = 32; off > 0; off >>= 1) {
      l0 += __shfl_xor(l0, off, 64);
      l1 += __shfl_xor(l1, off, 64);
    }
    float nm0 = fmaxf(m0, l0), nm1 = fmaxf(m1, l1);
    float sc0 = __expf(m0 - nm0), sc1 = __expf(m1 - nm1);
    float p0 = __expf(l0 - nm0), p1 = __expf(l1 - nm1);
    sum0 = sum0 * sc0 + p0;
    sum1 = sum1 * sc1 + p1;
    acc0 = acc0 * sc0 + p0 * cx0;
    acc1 = acc1 * sc1 + p1 * cx1;
    m0 = nm0; m1 = nm1;
  }

  float o0 = acc0 / (sum0 + 1e-16f) + bias[c0];
  float o1 = acc1 / (sum1 + 1e-16f) + bias[c1];
  o0 = o0 > 0.0f ? o0 : (expf(o0) - 1.0f);
  o1 = o1 > 0.0f ? o1 : (expf(o1) - 1.0f);
  hout[(size_t)n * HID + c0] = f2bf(o0);
  hout[(size_t)n * HID + c1] = f2bf(o1);
}

// ---------------- pool (+BN) and FC ----------------
__device__ __forceinline__ int lower_bound(const int* __restrict__ a, int n, int key) {
  int lo = 0, hi = n;
  while (lo < hi) { int mid = (lo + hi) >> 1; if (a[mid] < key) lo = mid + 1; else hi = mid; }
  return lo;
}

__global__ __launch_bounds__(256) void k_pool_bn(const unsigned short* __restrict__ h,
                                                 const int* __restrict__ batch,
                                                 const float* __restrict__ gamma,
                                                 const float* __restrict__ beta,
                                                 const float* __restrict__ mean,
                                                 const float* __restrict__ var,
                                                 float* __restrict__ gbn) {
  int g = blockIdx.x, t = threadIdx.x;
  int start = lower_bound(batch, NN, g);
  int end = lower_bound(batch, NN, g + 1);
  float a0 = 0.0f, a1 = 0.0f;
  for (int n = start; n < end; n++) {
    a0 += bf2f(h[(size_t)n * HID + t]);
    a1 += bf2f(h[(size_t)n * HID + t + 256]);
  }
  int c0 = t, c1 = t + 256;
  float v0 = (a0 - mean[c0]) * rsqrtf(var[c0] + 1e-5f) * gamma[c0] + beta[c0];
  float v1 = (a1 - mean[c1]) * rsqrtf(var[c1] + 1e-5f) * gamma[c1] + beta[c1];
  gbn[(size_t)g * HID + c0] = v0;
  gbn[(size_t)g * HID + c1] = v1;
}

__global__ __launch_bounds__(256) void k_fc(const float* __restrict__ gbn,
                                            const float* __restrict__ Wfc,
                                            const float* __restrict__ bfc,
                                            float* __restrict__ out) {
  __shared__ float xs[512];
  int g = blockIdx.x, t = threadIdx.x;
  xs[t] = gbn[g * 512 + t];
  xs[t + 256] = gbn[g * 512 + t + 256];
  __syncthreads();
  float acc = bfc[t];
#pragma unroll 8
  for (int k = 0; k < 512; k++) acc += xs[k] * Wfc[k * 256 + t];
  out[g * 256 + t] = acc;
}

extern "C" void kernel_launch(void* const* d_in, const int* in_sizes, int n_in,
                              void* d_out, int out_size, void* d_ws, size_t ws_size,
                              hipStream_t stream) {
  const float* x     = (const float*)d_in[0];
  const int* ei      = (const int*)d_in[1];
  const int* batch   = (const int*)d_in[2];
  const float* Wl0   = (const float*)d_in[3];
  const float* bl0   = (const float*)d_in[4];
  const float* Wr0   = (const float*)d_in[5];
  const float* br0   = (const float*)d_in[6];
  const float* att0  = (const float*)d_in[7];
  const float* bias0 = (const float*)d_in[8];
  const float* Wl1   = (const float*)d_in[9];
  const float* bl1   = (const float*)d_in[10];
  const float* Wr1   = (const float*)d_in[11];
  const float* br1   = (const float*)d_in[12];
  const float* att1  = (const float*)d_in[13];
  const float* bias1 = (const float*)d_in[14];
  const float* gamma = (const float*)d_in[15];
  const float* beta  = (const float*)d_in[16];
  const float* mean  = (const float*)d_in[17];
  const float* var   = (const float*)d_in[18];
  const float* Wfc   = (const float*)d_in[19];
  const float* bfc   = (const float*)d_in[20];

  const int* src = ei;
  const int* dst = ei + NE;

  char* w = (char*)d_ws;
  size_t off = 0;
  auto alloc = [&](size_t bytes) -> void* {
    void* p = w + off;
    off += (bytes + 255) & ~(size_t)255;
    return p;
  };
  int* deg            = (int*)alloc((size_t)NN * 4);
  int* offs           = (int*)alloc((size_t)(NN + 1) * 4);
  int* woff           = (int*)alloc((size_t)NN * 4);
  int* src_s          = (int*)alloc((size_t)NE * 4);
  unsigned short* xb  = (unsigned short*)alloc((size_t)NN * 256 * 2);
  unsigned short* xlr = (unsigned short*)alloc((size_t)NN * XLR_W * 2);
  unsigned short* hb  = (unsigned short*)alloc((size_t)NN * HID * 2);
  unsigned short* wt  = (unsigned short*)alloc((size_t)XLR_W * HID * 2);
  float* bcat         = (float*)alloc((size_t)XLR_W * 4);
  float* gbn          = (float*)alloc((size_t)NG * HID * 4);

  hipMemsetAsync(deg, 0, (size_t)NN * 4, stream);
  k_hist<<<(NE + 255) / 256, 256, 0, stream>>>(dst, deg, NE);
  k_scan<<<1, 1024, 0, stream>>>(deg, offs, woff, NN);
  k_scatter<<<(NE + 255) / 256, 256, 0, stream>>>(src, dst, woff, src_s, NE);

  k_cast<<<(NN * 256 / 4 + 255) / 256, 256, 0, stream>>>(x, xb, NN * 256 / 4);

  // layer 0
  k_pack<<<(XLR_W * 256 + 255) / 256, 256, 0, stream>>>(Wl0, bl0, Wr0, br0, wt, bcat, 256);
  k_gemm<<<dim3(XLR_W / BN, (NN + BM - 1) / BM), 256, 0, stream>>>(xb, wt, bcat, xlr, NN, XLR_W, 256);
  k_attn<<<NN, 256, 0, stream>>>(xlr, att0, offs, src_s, bias0, hb);

  // layer 1
  k_pack<<<(XLR_W * 512 + 255) / 256, 256, 0, stream>>>(Wl1, bl1, Wr1, br1, wt, bcat, 512);
  k_gemm<<<dim3(XLR_W / BN, (NN + BM - 1) / BM), 256, 0, stream>>>(hb, wt, bcat, xlr, NN, XLR_W, 512);
  k_attn<<<NN, 256, 0, stream>>>(xlr, att1, offs, src_s, bias1, hb);

  k_pool_bn<<<NG, 256, 0, stream>>>(hb, batch, gamma, beta, mean, var, gbn);
  k_fc<<<NG, 256, 0, stream>>>(gbn, Wfc, bfc, (float*)d_out);
}

// Round 4
// 442.424 us; speedup vs baseline: 1.7462x; 1.2288x over previous
//
#include <hip/hip_runtime.h>
#include <hip/hip_bf16.h>
#include <cstdint>

#define NN 20000
#define NE 200000
#define NG 128
#define HID 512
#define XLR_W 1024

typedef __attribute__((ext_vector_type(4))) float f32x4;
typedef __attribute__((ext_vector_type(8))) short s16x8;

__device__ __forceinline__ float bf2f(unsigned short u) {
  union { unsigned int i; float f; } v; v.i = ((unsigned int)u) << 16; return v.f;
}
__device__ __forceinline__ unsigned short f2bf(float f) {
  union { float f; unsigned int i; } v; v.f = f;
  unsigned int i = v.i + 0x7FFFu + ((v.i >> 16) & 1u);
  return (unsigned short)(i >> 16);
}
__device__ __forceinline__ float asf(unsigned int u) {
  union { unsigned int i; float f; } v; v.i = u; return v.f;
}

// ---------------- fp32 -> bf16 cast (values already bf16-rounded, so exact) ----------------
__global__ void k_cast(const float* __restrict__ in, unsigned short* __restrict__ out, int n4) {
  int i = blockIdx.x * blockDim.x + threadIdx.x;
  if (i < n4) {
    float4 v = ((const float4*)in)[i];
    ushort4 o;
    o.x = f2bf(v.x); o.y = f2bf(v.y); o.z = f2bf(v.z); o.w = f2bf(v.w);
    ((ushort4*)out)[i] = o;
  }
}

// ---------------- CSR build ----------------
__global__ void k_hist(const int* __restrict__ dst, int* __restrict__ deg, int E) {
  int i = blockIdx.x * blockDim.x + threadIdx.x;
  if (i < E) atomicAdd(&deg[dst[i]], 1);
}

__global__ void k_scan(const int* __restrict__ deg, int* __restrict__ offs,
                       int* __restrict__ woff, int n) {
  __shared__ int buf[1024];
  __shared__ int carry;
  int t = threadIdx.x;
  if (t == 0) carry = 0;
  __syncthreads();
  for (int base = 0; base < n; base += 1024) {
    int i = base + t;
    int v = (i < n) ? deg[i] : 0;
    buf[t] = v;
    __syncthreads();
    for (int off = 1; off < 1024; off <<= 1) {
      int x = (t >= off) ? buf[t - off] : 0;
      __syncthreads();
      buf[t] += x;
      __syncthreads();
    }
    int ex = buf[t] - v + carry;
    if (i < n) { offs[i] = ex; woff[i] = ex; }
    __syncthreads();
    if (t == 1023) carry += buf[1023];
    __syncthreads();
  }
  if (t == 0) offs[n] = carry;
}

__global__ void k_scatter(const int* __restrict__ src, const int* __restrict__ dst,
                          int* __restrict__ woff, int* __restrict__ src_s, int E) {
  int i = blockIdx.x * blockDim.x + threadIdx.x;
  if (i < E) {
    int d = dst[i];
    int pos = atomicAdd(&woff[d], 1);
    src_s[pos] = src[i];
  }
}

// ---------------- weight pack: wt[n][k] = W[k][n] (bf16), n in [0,1024) = Wl||Wr ----------------
__global__ void k_pack(const float* __restrict__ Wl, const float* __restrict__ bl,
                       const float* __restrict__ Wr, const float* __restrict__ br,
                       unsigned short* __restrict__ wt, float* __restrict__ bcat, int kshift) {
  int id = blockIdx.x * blockDim.x + threadIdx.x;
  int K = 1 << kshift;
  int total = XLR_W << kshift;
  if (id < total) {
    int nrow = id >> kshift, k = id & (K - 1);
    float v = (nrow < HID) ? Wl[k * HID + nrow] : Wr[k * HID + (nrow - HID)];
    wt[id] = f2bf(v);
  }
  if (id < XLR_W) bcat[id] = (id < HID) ? bl[id] : br[id - HID];
}

// ---------------- GEMM: C[M,N] = A[M,K] @ Bt[N,K]^T + bias, bf16 in/out, f32 acc ----------------
#define BM 128
#define BN 128
#define BK 32
#define LSTR 40

__global__ __launch_bounds__(256, 2) void k_gemm(const unsigned short* __restrict__ A,
                                                 const unsigned short* __restrict__ Bt,
                                                 const float* __restrict__ bias,
                                                 unsigned short* __restrict__ C,
                                                 int M, int N, int K) {
  __shared__ __align__(16) unsigned short As[BM * LSTR];
  __shared__ __align__(16) unsigned short Bs[BN * LSTR];
  int m0 = blockIdx.y * BM, n0 = blockIdx.x * BN;
  int t = threadIdx.x;
  int wave = t >> 6, lane = t & 63;
  int wm = (wave >> 1) * 64, wn = (wave & 1) * 64;
  int ml = lane & 15, mq = lane >> 4;
  int srow = t >> 2;
  int scol = (t & 3) * 8;

  f32x4 acc[4][4];
#pragma unroll
  for (int i = 0; i < 4; i++)
#pragma unroll
    for (int j = 0; j < 4; j++) acc[i][j] = (f32x4)0.0f;

  int ar0 = m0 + srow; if (ar0 > M - 1) ar0 = M - 1;
  int ar1 = m0 + srow + 64; if (ar1 > M - 1) ar1 = M - 1;
  const int4* a0p = (const int4*)(A + (size_t)ar0 * K + scol);
  const int4* a1p = (const int4*)(A + (size_t)ar1 * K + scol);
  const int4* b0p = (const int4*)(Bt + (size_t)(n0 + srow) * K + scol);
  const int4* b1p = (const int4*)(Bt + (size_t)(n0 + srow + 64) * K + scol);

  for (int k0 = 0; k0 < K; k0 += BK) {
    int4 av0 = *a0p; int4 av1 = *a1p; int4 bv0 = *b0p; int4 bv1 = *b1p;
    a0p += BK / 8; a1p += BK / 8; b0p += BK / 8; b1p += BK / 8;
    *(int4*)(&As[srow * LSTR + scol]) = av0;
    *(int4*)(&As[(srow + 64) * LSTR + scol]) = av1;
    *(int4*)(&Bs[srow * LSTR + scol]) = bv0;
    *(int4*)(&Bs[(srow + 64) * LSTR + scol]) = bv1;
    __syncthreads();
    s16x8 af[4], bfr[4];
#pragma unroll
    for (int i = 0; i < 4; i++)
      af[i] = *(const s16x8*)(&As[(wm + i * 16 + ml) * LSTR + mq * 8]);
#pragma unroll
    for (int j = 0; j < 4; j++)
      bfr[j] = *(const s16x8*)(&Bs[(wn + j * 16 + ml) * LSTR + mq * 8]);
#pragma unroll
    for (int i = 0; i < 4; i++)
#pragma unroll
      for (int j = 0; j < 4; j++)
        acc[i][j] = __builtin_amdgcn_mfma_f32_16x16x32_bf16(af[i], bfr[j], acc[i][j], 0, 0, 0);
    __syncthreads();
  }

#pragma unroll
  for (int i = 0; i < 4; i++) {
#pragma unroll
    for (int j = 0; j < 4; j++) {
      int col = n0 + wn + j * 16 + ml;
      float bcol = bias[col];
#pragma unroll
      for (int r = 0; r < 4; r++) {
        int row = m0 + wm + i * 16 + mq * 4 + r;
        if (row < M) C[(size_t)row * N + col] = f2bf(acc[i][j][r] + bcol);
      }
    }
  }
}

// ---------------- fused attention: logits + online softmax + aggregate + bias + ELU ----------------
// block per dst node; 4 waves; each half-wave = one head, 2 channels/lane (packed uint).
__global__ __launch_bounds__(256) void k_attn(const unsigned short* __restrict__ xlr,
                                              const float* __restrict__ att,
                                              const int* __restrict__ offs,
                                              const int* __restrict__ src_s,
                                              const float* __restrict__ bias,
                                              unsigned short* __restrict__ hout) {
  int n = blockIdx.x;
  int wave = threadIdx.x >> 6, lane = threadIdx.x & 63;
  int half = lane >> 5, sl = lane & 31;
  int h = wave * 2 + half;
  int c = h * 64 + sl * 2;  // channel pair (c, c+1), byte-aligned to 4
  int s0 = offs[n], s1 = offs[n + 1];

  // xr[dst] pair + att pair (register-resident)
  unsigned int uxr = *(const unsigned int*)(xlr + (size_t)n * XLR_W + HID + c);
  float xr_a = asf(uxr << 16), xr_b = asf(uxr & 0xFFFF0000u);
  float at_a = att[c], at_b = att[c + 1];

  float m = -3.0e38f, sum = 0.0f, acc_a = 0.0f, acc_b = 0.0f;

  // 2-deep pipeline
  int sA = (s0 < s1) ? src_s[s0] : 0;
  unsigned int u_cur = (s0 < s1) ? *(const unsigned int*)(xlr + (size_t)sA * XLR_W + c) : 0u;
  int sB = (s0 + 1 < s1) ? src_s[s0 + 1] : 0;

  for (int i = s0; i < s1; i++) {
    unsigned int u = u_cur;
    if (i + 1 < s1) u_cur = *(const unsigned int*)(xlr + (size_t)sB * XLR_W + c);
    if (i + 2 < s1) sB = src_s[i + 2];

    float xl_a = asf(u << 16), xl_b = asf(u & 0xFFFF0000u);
    float v_a = xl_a + xr_a; v_a = v_a > 0.0f ? v_a : 0.2f * v_a;
    float v_b = xl_b + xr_b; v_b = v_b > 0.0f ? v_b : 0.2f * v_b;
    float l = v_a * at_a + v_b * at_b;
#pragma unroll
    for (int off = 16; off > 0; off >>= 1) l += __shfl_xor(l, off, 64);  // within half-wave

    float nm = fmaxf(m, l);
    float sc = __expf(m - nm);
    float p = __expf(l - nm);
    sum = sum * sc + p;
    acc_a = acc_a * sc + p * xl_a;
    acc_b = acc_b * sc + p * xl_b;
    m = nm;
  }

  float di = 1.0f / (sum + 1e-16f);
  float o_a = acc_a * di + bias[c];
  float o_b = acc_b * di + bias[c + 1];
  o_a = o_a > 0.0f ? o_a : (expf(o_a) - 1.0f);
  o_b = o_b > 0.0f ? o_b : (expf(o_b) - 1.0f);
  unsigned int up = (unsigned int)f2bf(o_a) | ((unsigned int)f2bf(o_b) << 16);
  *(unsigned int*)(hout + (size_t)n * HID + c) = up;
}

// ---------------- pool (partial sums, 2 blocks per graph) ----------------
__device__ __forceinline__ int lower_bound(const int* __restrict__ a, int n, int key) {
  int lo = 0, hi = n;
  while (lo < hi) { int mid = (lo + hi) >> 1; if (a[mid] < key) lo = mid + 1; else hi = mid; }
  return lo;
}

__global__ __launch_bounds__(256) void k_pool(const unsigned short* __restrict__ h,
                                              const int* __restrict__ batch,
                                              float* __restrict__ part) {
  int g = blockIdx.x, p = blockIdx.y, t = threadIdx.x;
  int start = lower_bound(batch, NN, g);
  int end = lower_bound(batch, NN, g + 1);
  int mid = start + ((end - start + 1) >> 1);
  int lo = p ? mid : start;
  int hi = p ? end : mid;
  int c = t * 2;
  float a0 = 0.0f, a1 = 0.0f;
  for (int n = lo; n < hi; n++) {
    unsigned int u = *(const unsigned int*)(h + (size_t)n * HID + c);
    a0 += asf(u << 16);
    a1 += asf(u & 0xFFFF0000u);
  }
  float* dstp = part + ((size_t)g * 2 + p) * HID + c;
  dstp[0] = a0;
  dstp[1] = a1;
}

// ---------------- BN + FC fused ----------------
__global__ __launch_bounds__(256) void k_fc(const float* __restrict__ part,
                                            const float* __restrict__ gamma,
                                            const float* __restrict__ beta,
                                            const float* __restrict__ mean,
                                            const float* __restrict__ var,
                                            const float* __restrict__ Wfc,
                                            const float* __restrict__ bfc,
                                            float* __restrict__ out) {
  __shared__ float xs[512];
  int g = blockIdx.x, t = threadIdx.x;
  for (int c = t; c < HID; c += 256) {
    float s = part[(size_t)g * 2 * HID + c] + part[((size_t)g * 2 + 1) * HID + c];
    xs[c] = (s - mean[c]) * rsqrtf(var[c] + 1e-5f) * gamma[c] + beta[c];
  }
  __syncthreads();
  float acc = bfc[t];
#pragma unroll 8
  for (int k = 0; k < 512; k++) acc += xs[k] * Wfc[k * 256 + t];
  out[g * 256 + t] = acc;
}

extern "C" void kernel_launch(void* const* d_in, const int* in_sizes, int n_in,
                              void* d_out, int out_size, void* d_ws, size_t ws_size,
                              hipStream_t stream) {
  const float* x     = (const float*)d_in[0];
  const int* ei      = (const int*)d_in[1];
  const int* batch   = (const int*)d_in[2];
  const float* Wl0   = (const float*)d_in[3];
  const float* bl0   = (const float*)d_in[4];
  const float* Wr0   = (const float*)d_in[5];
  const float* br0   = (const float*)d_in[6];
  const float* att0  = (const float*)d_in[7];
  const float* bias0 = (const float*)d_in[8];
  const float* Wl1   = (const float*)d_in[9];
  const float* bl1   = (const float*)d_in[10];
  const float* Wr1   = (const float*)d_in[11];
  const float* br1   = (const float*)d_in[12];
  const float* att1  = (const float*)d_in[13];
  const float* bias1 = (const float*)d_in[14];
  const float* gamma = (const float*)d_in[15];
  const float* beta  = (const float*)d_in[16];
  const float* mean  = (const float*)d_in[17];
  const float* var   = (const float*)d_in[18];
  const float* Wfc   = (const float*)d_in[19];
  const float* bfc   = (const float*)d_in[20];

  const int* src = ei;
  const int* dst = ei + NE;

  char* w = (char*)d_ws;
  size_t off = 0;
  auto alloc = [&](size_t bytes) -> void* {
    void* p = w + off;
    off += (bytes + 255) & ~(size_t)255;
    return p;
  };
  int* deg            = (int*)alloc((size_t)NN * 4);
  int* offs           = (int*)alloc((size_t)(NN + 1) * 4);
  int* woff           = (int*)alloc((size_t)NN * 4);
  int* src_s          = (int*)alloc((size_t)NE * 4);
  unsigned short* xb  = (unsigned short*)alloc((size_t)NN * 256 * 2);
  unsigned short* xlr = (unsigned short*)alloc((size_t)NN * XLR_W * 2);
  unsigned short* hb  = (unsigned short*)alloc((size_t)NN * HID * 2);
  unsigned short* wt  = (unsigned short*)alloc((size_t)XLR_W * HID * 2);
  float* bcat         = (float*)alloc((size_t)XLR_W * 4);
  float* part         = (float*)alloc((size_t)NG * 2 * HID * 4);

  hipMemsetAsync(deg, 0, (size_t)NN * 4, stream);
  k_hist<<<(NE + 255) / 256, 256, 0, stream>>>(dst, deg, NE);
  k_scan<<<1, 1024, 0, stream>>>(deg, offs, woff, NN);
  k_scatter<<<(NE + 255) / 256, 256, 0, stream>>>(src, dst, woff, src_s, NE);

  k_cast<<<(NN * 256 / 4 + 255) / 256, 256, 0, stream>>>(x, xb, NN * 256 / 4);

  // layer 0
  k_pack<<<(XLR_W * 256 + 255) / 256, 256, 0, stream>>>(Wl0, bl0, Wr0, br0, wt, bcat, 8);
  k_gemm<<<dim3(XLR_W / BN, (NN + BM - 1) / BM), 256, 0, stream>>>(xb, wt, bcat, xlr, NN, XLR_W, 256);
  k_attn<<<NN, 256, 0, stream>>>(xlr, att0, offs, src_s, bias0, hb);

  // layer 1
  k_pack<<<(XLR_W * 512 + 255) / 256, 256, 0, stream>>>(Wl1, bl1, Wr1, br1, wt, bcat, 9);
  k_gemm<<<dim3(XLR_W / BN, (NN + BM - 1) / BM), 256, 0, stream>>>(hb, wt, bcat, xlr, NN, XLR_W, 512);
  k_attn<<<NN, 256, 0, stream>>>(xlr, att1, offs, src_s, bias1, hb);

  k_pool<<<dim3(NG, 2), 256, 0, stream>>>(hb, batch, part);
  k_fc<<<NG, 256, 0, stream>>>(part, gamma, beta, mean, var, Wfc, bfc, (float*)d_out);
}